// Round 5
// baseline (326.957 us; speedup 1.0000x reference)
//
#include <hip/hip_runtime.h>
#include <stdint.h>

// Problem constants
#define NB 8192
#define NE 16
#define ND 128
#define NU 256
#define NF 256
#define NG 4
#define NK 6
#define ITEMP_LOG2E 144.26950408889634f  // (1/0.01) * log2(e)

typedef short short4v __attribute__((ext_vector_type(4)));
typedef short short8v __attribute__((ext_vector_type(8)));
typedef float float4v __attribute__((ext_vector_type(4)));

__device__ __forceinline__ short f2bf(float x) {
  uint32_t u = __builtin_bit_cast(uint32_t, x);
  u += 0x7FFFu + ((u >> 16) & 1u);       // round-to-nearest-even
  return (short)(u >> 16);
}

// ---------------------------------------------------------------------------
// prep kernel: pack expert_kernels fp32 -> bf16 in MFMA B-fragment order.
// v4: pb layout is ut-major [ut][e][ks][lane] so each moe wave's B-frag
// reads are one contiguous 64KB stream (was stride-16KB scatter).
// ---------------------------------------------------------------------------
__global__ __launch_bounds__(256) void prep_kernel(
    const float* __restrict__ ek,     // [E,D,U]
    short* __restrict__ pb)           // packed B frags: 65536*8 bf16
{
  // frag element (e,ks,ut,lane,j) = ek[e][ks*32+(lane>>4)*8+j][ut*16+(lane&15)]
  int gid = (blockIdx.x << 8) | threadIdx.x;   // [0, 65536)
  int lane = gid & 63, ut = (gid >> 6) & 15, ks = (gid >> 10) & 3, e = gid >> 12;
  int krow = ks * 32 + ((lane >> 4) * 8);
  int ucol = ut * 16 + (lane & 15);
  const float* src = ek + (size_t)(e * 128 + krow) * 256 + ucol;
  short8v v;
#pragma unroll
  for (int j = 0; j < 8; ++j) v[j] = f2bf(src[(size_t)j * 256]);
  size_t widx = (((size_t)ut * 16 + e) * 4 + ks) * 64 + lane;  // ut-major
  *(short8v*)(pb + widx * 8) = v;
}

// ---------------------------------------------------------------------------
// main kernel v4: 256 blocks x 1024 threads (16 waves), 32 b-rows per block.
// v3 post-mortem: dur invariant (146->143us) while bytes halved => latency-
// serialization, not BW. v4 pipelines every serial chain:
//  - staging (waves 0-11): 11-deep register load batches, then convert+write
//    (exposed HBM latency ~2x900cy instead of ~20x900cy per wave)
//  - gating (waves 12-15, 8 rows each): 16-deep gk preload batches; halves
//    the pre-barrier critical path vs 2 waves
//  - MFMA loop: ut-major pb stream + explicit alternating 4-reg B prefetch
//  - stores stay plain (v3's byte win: WRITE 206MB vs nt's 376MB)
// ---------------------------------------------------------------------------
#define APITCH 2056  // shorts per A row: 2048 + 8 pad (bank step 4 -> 2-way, free)
#define WPITCH 64    // floats per wd row (combine reads are 16-lane broadcast)

__global__ __launch_bounds__(1024, 4) void moe_kernel(
    const float* __restrict__ x,     // [B, E*D]
    const float* __restrict__ feat,  // [B, F]
    const float* __restrict__ gk,    // [G, F, E]
    const float* __restrict__ gbias, // [G, E]
    const float* __restrict__ gw,    // [E]
    const float* __restrict__ eb,    // [E, U]
    const short* __restrict__ pb,    // packed bf16 B frags (ut-major)
    float* __restrict__ out)         // concat [B,G*U] then eo [B,U,E]
{
  __shared__ __align__(16) short ash[32 * APITCH];  // 131584 B
  __shared__ __align__(16) float wsh[32 * WPITCH];  // 8192 B
  __shared__ __align__(16) float stg[16 * 256];     // 16384 B (1KB per wave)
  int bt = blockIdx.x, tid = threadIdx.x;
  int w = tid >> 6, lane = tid & 63;

  if (w < 12) {
    // ---- A-tile staging: 32 rows x 512 f4 = 16384 f4, 12 waves = 768 lanes.
    // 21 full strides + 256-element tail (exactly waves 0-3).
    const float4v* s = (const float4v*)(x + (size_t)bt * 32 * 2048);
    int base = w * 64 + lane;            // [0, 768)
    float4v buf[11];
    // chunk 1: k = 0..10 (11 loads in flight, then convert)
#pragma unroll
    for (int k = 0; k < 11; ++k) buf[k] = __builtin_nontemporal_load(s + base + k * 768);
#pragma unroll
    for (int k = 0; k < 11; ++k) {
      int idx = base + k * 768;
      int row = idx >> 9, colf = (idx & 511) << 2;
      short4v sv;
      sv[0] = f2bf(buf[k][0]); sv[1] = f2bf(buf[k][1]);
      sv[2] = f2bf(buf[k][2]); sv[3] = f2bf(buf[k][3]);
      *(short4v*)&ash[row * APITCH + colf] = sv;
    }
    // chunk 2: k = 11..20 (10 loads)
#pragma unroll
    for (int k = 0; k < 10; ++k) buf[k] = __builtin_nontemporal_load(s + base + (11 + k) * 768);
#pragma unroll
    for (int k = 0; k < 10; ++k) {
      int idx = base + (11 + k) * 768;
      int row = idx >> 9, colf = (idx & 511) << 2;
      short4v sv;
      sv[0] = f2bf(buf[k][0]); sv[1] = f2bf(buf[k][1]);
      sv[2] = f2bf(buf[k][2]); sv[3] = f2bf(buf[k][3]);
      *(short4v*)&ash[row * APITCH + colf] = sv;
    }
    // tail: last 256 f4 (bases 0..255 == waves 0-3)
    if (base < 256) {
      int idx = base + 16128;
      float4v v = __builtin_nontemporal_load(s + idx);
      int row = idx >> 9, colf = (idx & 511) << 2;
      short4v sv;
      sv[0] = f2bf(v[0]); sv[1] = f2bf(v[1]); sv[2] = f2bf(v[2]); sv[3] = f2bf(v[3]);
      *(short4v*)&ash[row * APITCH + colf] = sv;
    }
  } else {
    // ---- gating: 4 waves x 8 rows (rows (w-12)*8 .. +7)
    int rb = (w - 12) * 8;
    int gate = lane >> 4, e = lane & 15;   // lane = (gate, expert)
    float gwv = gw[e];
    float bias = gbias[gate * 16 + e];
    const float* gkp = gk + (size_t)gate * (NF * NE) + e;
    const float* fb = feat + ((size_t)bt * 32 + rb) * 256;
    float acc[8];
#pragma unroll
    for (int i = 0; i < 8; ++i) acc[i] = bias;
#pragma unroll 1
    for (int f0 = 0; f0 < NF; f0 += 16) {
      float gv[16];
#pragma unroll
      for (int j = 0; j < 16; ++j) gv[j] = gkp[(f0 + j) * 16];
#pragma unroll
      for (int j = 0; j < 16; j += 4) {
#pragma unroll
        for (int i = 0; i < 8; ++i) {      // feat read is wave-uniform (broadcast)
          float4v fv = *(const float4v*)(fb + i * 256 + f0 + j);
          acc[i] = fmaf(fv[0], gv[j + 0], acc[i]);
          acc[i] = fmaf(fv[1], gv[j + 1], acc[i]);
          acc[i] = fmaf(fv[2], gv[j + 2], acc[i]);
          acc[i] = fmaf(fv[3], gv[j + 3], acc[i]);
        }
      }
    }
#pragma unroll 1
    for (int i = 0; i < 8; ++i) {
      float v = acc[i] > 0.f ? acc[i] : 0.f;  // relu
      v *= gwv;                               // * global_weights
      // sharp softmax over 16 experts (within 16-lane group)
      float m = v;
#pragma unroll
      for (int off = 1; off < 16; off <<= 1) m = fmaxf(m, __shfl_xor(m, off, 16));
      float ex = exp2f((v - m) * ITEMP_LOG2E);
      float s = ex;
#pragma unroll
      for (int off = 1; off < 16; off <<= 1) s += __shfl_xor(s, off, 16);
      float pr = ex / s;
      // iterative top-6 (max value, min-index tie-break = jax top_k order)
      float cur = pr;
      float topv[NK]; int topi[NK];
#pragma unroll
      for (int r = 0; r < NK; ++r) {
        float mv = cur;
#pragma unroll
        for (int off = 1; off < 16; off <<= 1) mv = fmaxf(mv, __shfl_xor(mv, off, 16));
        int cand = (cur == mv) ? e : 16;
#pragma unroll
        for (int off = 1; off < 16; off <<= 1) cand = min(cand, __shfl_xor(cand, off, 16));
        topv[r] = mv; topi[r] = cand;
        if (e == cand) cur = -1.f;
      }
      // second sharp softmax over the 6 selected (topv[0] is the max)
      float wv[NK], wsum = 0.f;
#pragma unroll
      for (int r = 0; r < NK; ++r) {
        wv[r] = exp2f((topv[r] - topv[0]) * ITEMP_LOG2E);
        wsum += wv[r];
      }
      float inv = 1.f / wsum;
      float wdv = 0.f;
#pragma unroll
      for (int r = 0; r < NK; ++r) wdv = (topi[r] == e) ? wv[r] * inv : wdv;
      wsh[(rb + i) * WPITCH + lane] = wdv;  // gate*16+e == lane
    }
  }
  __syncthreads();

  // ---- compute: 16 waves = 2 btile x 4 utq x 2 th; each wave 2 u-tiles
  int btile = w >> 3, utq = (w >> 1) & 3, th = w & 1;
  int q = lane >> 4, col = lane & 15;   // C/D frag: row=q*4+r, col=lane&15
  int am = lane & 15;                   // A frag: m = lane&15
  float* outcat = out;
  float* outeo = out + (size_t)NB * NG * NU;
  const short8v* pbv = (const short8v*)pb;
  float* ws = stg + w * 256;            // this wave's 1KB staging slice
  size_t bb = (size_t)bt * 32 + btile * 16;
  int arow = (btile * 16 + am) * APITCH;
  int wrow = (btile * 16 + q * 4) * WPITCH;

  float csave[4][4];                    // concat values from tl=0, flushed at tl=1

#pragma unroll 1
  for (int tl = 0; tl < 2; ++tl) {
    int t = th * 2 + tl;
    int ut = utq * 4 + t;               // this wave's u-tile
    const short8v* bp = pbv + (size_t)ut * 4096;  // contiguous 64KB stream
    float4v acc[16];
    float4v zero = {0.f, 0.f, 0.f, 0.f};
#pragma unroll
    for (int e = 0; e < 16; ++e) acc[e] = zero;
    // explicit alternating B prefetch, 2-expert distance
    short8v bA[4], bB[4];
#pragma unroll
    for (int ks = 0; ks < 4; ++ks) bA[ks] = bp[ks * 64 + lane];
#pragma unroll
    for (int e = 0; e < 16; e += 2) {
#pragma unroll
      for (int ks = 0; ks < 4; ++ks) bB[ks] = bp[(e + 1) * 256 + ks * 64 + lane];
#pragma unroll
      for (int ks = 0; ks < 4; ++ks) {
        short8v a = *(const short8v*)&ash[arow + e * 128 + ks * 32 + q * 8];
        acc[e] = __builtin_amdgcn_mfma_f32_16x16x32_bf16(a, bA[ks], acc[e], 0, 0, 0);
      }
      if (e + 2 < 16) {
#pragma unroll
        for (int ks = 0; ks < 4; ++ks) bA[ks] = bp[(e + 2) * 256 + ks * 64 + lane];
      }
#pragma unroll
      for (int ks = 0; ks < 4; ++ks) {
        short8v a = *(const short8v*)&ash[arow + (e + 1) * 128 + ks * 32 + q * 8];
        acc[e + 1] = __builtin_amdgcn_mfma_f32_16x16x32_bf16(a, bB[ks], acc[e + 1], 0, 0, 0);
      }
    }
    // bias + leaky_relu
    float v[16][4];
#pragma unroll
    for (int e = 0; e < 16; ++e) {
      float bv = eb[e * 256 + ut * 16 + col];
#pragma unroll
      for (int r = 0; r < 4; ++r) {
        float z = acc[e][r] + bv;
        v[e][r] = z > 0.f ? z : 0.2f * z;
      }
    }
    // eo writes via per-wave LDS transpose: 4 rounds (one q each) per r.
    // write slot c*16+col (16 consecutive float4 -> conflict-free), read
    // slot lane (linear). Each flush = contiguous 1KB (b,ut) region.
#pragma unroll
    for (int r = 0; r < 4; ++r) {
#pragma unroll
      for (int qq = 0; qq < 4; ++qq) {
        if (q == qq) {
#pragma unroll
          for (int c = 0; c < 4; ++c) {
            float4v o = {v[4 * c + 0][r], v[4 * c + 1][r], v[4 * c + 2][r], v[4 * c + 3][r]};
            *(float4v*)(ws + (c * 16 + col) * 4) = o;
          }
        }
        __builtin_amdgcn_wave_barrier();   // fence: write -> read (wave-synchronous LDS)
        {
          size_t b = bb + (size_t)(qq * 4 + r);
          float4v val = *(const float4v*)(ws + lane * 4);  // linear, conflict-free
          float* dst = outeo + b * 4096 + (size_t)ut * 256 + (lane & 15) * 16 + (lane >> 4) * 4;
          *(float4v*)dst = val;            // plain store: full dirty lines via L2
        }
        __builtin_amdgcn_wave_barrier();   // fence: read -> next round's write
      }
    }
    // dense combine: out[b,g,u] = sum_e wd[b,g,e] * eo[b,u,e]
    // pair stores across (tl=0, tl=1): adjacent 64B halves of one 128B line.
#pragma unroll
    for (int r = 0; r < 4; ++r) {
      size_t b = bb + (size_t)(q * 4 + r);
#pragma unroll
      for (int g = 0; g < 4; ++g) {
        float sacc = 0.f;
#pragma unroll
        for (int ec = 0; ec < 16; ec += 4) {
          float4v wv = *(const float4v*)&wsh[wrow + r * WPITCH + g * 16 + ec];
          sacc = fmaf(wv[0], v[ec][r], sacc);
          sacc = fmaf(wv[1], v[ec + 1][r], sacc);
          sacc = fmaf(wv[2], v[ec + 2][r], sacc);
          sacc = fmaf(wv[3], v[ec + 3][r], sacc);
        }
        if (tl == 0) {
          csave[r][g] = sacc;
        } else {
          float* cb = outcat + b * 1024 + g * 256 + (ut - 1) * 16 + col;
          cb[0] = csave[r][g];
          cb[16] = sacc;
        }
      }
    }
  }
}

extern "C" void kernel_launch(void* const* d_in, const int* in_sizes, int n_in,
                              void* d_out, int out_size, void* d_ws, size_t ws_size,
                              hipStream_t stream) {
  const float* x     = (const float*)d_in[0];  // [B, E*D]
  const float* feat  = (const float*)d_in[1];  // [B, F]
  const float* ek    = (const float*)d_in[2];  // [E, D, U]
  const float* eb    = (const float*)d_in[3];  // [E, U]
  const float* gk    = (const float*)d_in[4];  // [G, F, E]
  const float* gbias = (const float*)d_in[5];  // [G, E]
  const float* gw    = (const float*)d_in[6];  // [E]
  float* out = (float*)d_out;
  short* pbf = (short*)d_ws;                   // 1MB packed bf16 B frags

  prep_kernel<<<256, 256, 0, stream>>>(ek, pbf);
  moe_kernel<<<256, 1024, 0, stream>>>(x, feat, gk, gbias, gw, eb, pbf, out);
}

// Round 6
// 323.020 us; speedup vs baseline: 1.0122x; 1.0122x over previous
//
#include <hip/hip_runtime.h>
#include <stdint.h>

// Problem constants
#define NB 8192
#define NE 16
#define ND 128
#define NU 256
#define NF 256
#define NG 4
#define NK 6
#define ITEMP_LOG2E 144.26950408889634f  // (1/0.01) * log2(e)

typedef short short4v __attribute__((ext_vector_type(4)));
typedef short short8v __attribute__((ext_vector_type(8)));
typedef float float4v __attribute__((ext_vector_type(4)));

__device__ __forceinline__ short f2bf(float x) {
  uint32_t u = __builtin_bit_cast(uint32_t, x);
  u += 0x7FFFu + ((u >> 16) & 1u);       // round-to-nearest-even
  return (short)(u >> 16);
}

// ---------------------------------------------------------------------------
// prep kernel: blocks [0,256) pack expert_kernels fp32 -> bf16 (ut-major
// [ut][e][ks][lane] so gemm waves read a contiguous 64KB stream);
// blocks [256,512) compute gating -> dense weights wd[b,g,e] (register-
// blocked 16-deep gk preloads, 4 waves x 8 rows).
// ---------------------------------------------------------------------------
__global__ __launch_bounds__(256) void prep_kernel(
    const float* __restrict__ ek,     // [E,D,U]
    const float* __restrict__ feat,   // [B,F]
    const float* __restrict__ gk,     // [G,F,E]
    const float* __restrict__ gbias,  // [G,E]
    const float* __restrict__ gw,     // [E]
    short* __restrict__ pb,           // packed B frags: 65536*8 bf16
    float* __restrict__ wd)           // [B,G,E] dense weights
{
  int bid = blockIdx.x, tid = threadIdx.x;
  if (bid < 256) {
    // pack: frag element (e,ks,ut,lane,j) = ek[e][ks*32+(lane>>4)*8+j][ut*16+(lane&15)]
    int gid = (bid << 8) | tid;              // [0, 65536)
    int lane = gid & 63, ut = (gid >> 6) & 15, ks = (gid >> 10) & 3, e = gid >> 12;
    int krow = ks * 32 + ((lane >> 4) * 8);
    int ucol = ut * 16 + (lane & 15);
    const float* src = ek + (size_t)(e * 128 + krow) * 256 + ucol;
    short8v v;
#pragma unroll
    for (int j = 0; j < 8; ++j) v[j] = f2bf(src[(size_t)j * 256]);
    size_t widx = (((size_t)ut * 16 + e) * 4 + ks) * 64 + lane;  // ut-major
    *(short8v*)(pb + widx * 8) = v;
  } else {
    // ---- gating: 4 waves x 8 rows each; 32 b-rows per block
    int w = tid >> 6, lane = tid & 63;
    int rb = w * 8;
    int gate = lane >> 4, e = lane & 15;   // lane = (gate, expert)
    float gwv = gw[e];
    float bias = gbias[gate * 16 + e];
    const float* gkp = gk + (size_t)gate * (NF * NE) + e;
    size_t b0 = (size_t)(bid - 256) * 32 + rb;
    const float* fb = feat + b0 * 256;
    float acc[8];
#pragma unroll
    for (int i = 0; i < 8; ++i) acc[i] = bias;
#pragma unroll 1
    for (int f0 = 0; f0 < NF; f0 += 16) {
      float gv[16];
#pragma unroll
      for (int j = 0; j < 16; ++j) gv[j] = gkp[(f0 + j) * 16];
#pragma unroll
      for (int j = 0; j < 16; j += 4) {
#pragma unroll
        for (int i = 0; i < 8; ++i) {      // feat read is wave-uniform (broadcast)
          float4v fv = *(const float4v*)(fb + i * 256 + f0 + j);
          acc[i] = fmaf(fv[0], gv[j + 0], acc[i]);
          acc[i] = fmaf(fv[1], gv[j + 1], acc[i]);
          acc[i] = fmaf(fv[2], gv[j + 2], acc[i]);
          acc[i] = fmaf(fv[3], gv[j + 3], acc[i]);
        }
      }
    }
#pragma unroll 1
    for (int i = 0; i < 8; ++i) {
      float v = acc[i] > 0.f ? acc[i] : 0.f;  // relu
      v *= gwv;                               // * global_weights
      // sharp softmax over 16 experts (within 16-lane group)
      float m = v;
#pragma unroll
      for (int off = 1; off < 16; off <<= 1) m = fmaxf(m, __shfl_xor(m, off, 16));
      float ex = exp2f((v - m) * ITEMP_LOG2E);
      float s = ex;
#pragma unroll
      for (int off = 1; off < 16; off <<= 1) s += __shfl_xor(s, off, 16);
      float pr = ex / s;
      // iterative top-6 (max value, min-index tie-break = jax top_k order)
      float cur = pr;
      float topv[NK]; int topi[NK];
#pragma unroll
      for (int r = 0; r < NK; ++r) {
        float mv = cur;
#pragma unroll
        for (int off = 1; off < 16; off <<= 1) mv = fmaxf(mv, __shfl_xor(mv, off, 16));
        int cand = (cur == mv) ? e : 16;
#pragma unroll
        for (int off = 1; off < 16; off <<= 1) cand = min(cand, __shfl_xor(cand, off, 16));
        topv[r] = mv; topi[r] = cand;
        if (e == cand) cur = -1.f;
      }
      // second sharp softmax over the 6 selected (topv[0] is the max)
      float wv[NK], wsum = 0.f;
#pragma unroll
      for (int r = 0; r < NK; ++r) {
        wv[r] = exp2f((topv[r] - topv[0]) * ITEMP_LOG2E);
        wsum += wv[r];
      }
      float inv = 1.f / wsum;
      float wdv = 0.f;
#pragma unroll
      for (int r = 0; r < NK; ++r) wdv = (topi[r] == e) ? wv[r] * inv : wdv;
      wd[(b0 + i) * 64 + lane] = wdv;   // dense [B,G,E]; 256B/instr, full lines
    }
  }
}

// ---------------------------------------------------------------------------
// gemm kernel v5: 512 blocks x 512 threads (8 waves), 16 b-rows per block.
// LDS 74KB -> 2 blocks/CU: block N+1's staging overlaps block N's compute
// (v2-v4 were 1 block/CU: stage->barrier->compute fully serialized per CU,
// the suspected fixed ~140us). No gating, no combine here (bisection).
// ---------------------------------------------------------------------------
#define APITCH 2056  // shorts per A row: 2048 + 8 pad (bank step 4 -> 2-way, free)

__global__ __launch_bounds__(512, 4) void gemm_kernel(
    const float* __restrict__ x,     // [B, E*D]
    const float* __restrict__ eb,    // [E, U]
    const short* __restrict__ pb,    // packed bf16 B frags (ut-major)
    float* __restrict__ outeo)       // eo [B,U,E]
{
  __shared__ __align__(16) short ash[16 * APITCH];  // 65792 B
  __shared__ __align__(16) float stg[8 * 256];      // 8192 B (1KB per wave)
  int bt = blockIdx.x, tid = threadIdx.x;
  int w = tid >> 6, lane = tid & 63;

  // ---- A-tile staging: 16 rows x 512 f4 = 8192 f4, 512 threads x 16, 8-deep
  {
    const float4v* s = (const float4v*)(x + (size_t)bt * 16 * 2048);
    float4v buf[8];
#pragma unroll
    for (int c = 0; c < 2; ++c) {
#pragma unroll
      for (int k = 0; k < 8; ++k)
        buf[k] = __builtin_nontemporal_load(s + tid + (c * 8 + k) * 512);
#pragma unroll
      for (int k = 0; k < 8; ++k) {
        int idx = tid + (c * 8 + k) * 512;
        int row = idx >> 9, colf = (idx & 511) << 2;
        short4v sv;
        sv[0] = f2bf(buf[k][0]); sv[1] = f2bf(buf[k][1]);
        sv[2] = f2bf(buf[k][2]); sv[3] = f2bf(buf[k][3]);
        *(short4v*)&ash[row * APITCH + colf] = sv;
      }
    }
  }
  __syncthreads();

  // ---- compute: 8 waves = 4 utq x 2 th; each wave 2 u-tiles (tl loop)
  int utq = w & 3, th = w >> 2;
  int q = lane >> 4, col = lane & 15;   // C/D frag: row=q*4+r, col=lane&15
  int am = lane & 15;                   // A frag: m = lane&15
  const short8v* pbv = (const short8v*)pb;
  float* ws = stg + w * 256;            // this wave's 1KB staging slice
  size_t bb = (size_t)bt * 16;
  int arow = am * APITCH;

#pragma unroll 1
  for (int tl = 0; tl < 2; ++tl) {
    int ut = utq * 4 + th * 2 + tl;     // coverage: 8 waves x 2 = ut 0..15
    const short8v* bp = pbv + (size_t)ut * 4096;  // contiguous 64KB stream
    float4v acc[16];
    float4v zero = {0.f, 0.f, 0.f, 0.f};
#pragma unroll
    for (int e = 0; e < 16; ++e) acc[e] = zero;
    // explicit alternating B prefetch, 2-expert distance
    short8v bA[4], bB[4];
#pragma unroll
    for (int ks = 0; ks < 4; ++ks) bA[ks] = bp[ks * 64 + lane];
#pragma unroll
    for (int e = 0; e < 16; e += 2) {
#pragma unroll
      for (int ks = 0; ks < 4; ++ks) bB[ks] = bp[(e + 1) * 256 + ks * 64 + lane];
#pragma unroll
      for (int ks = 0; ks < 4; ++ks) {
        short8v a = *(const short8v*)&ash[arow + e * 128 + ks * 32 + q * 8];
        acc[e] = __builtin_amdgcn_mfma_f32_16x16x32_bf16(a, bA[ks], acc[e], 0, 0, 0);
      }
      if (e + 2 < 16) {
#pragma unroll
        for (int ks = 0; ks < 4; ++ks) bA[ks] = bp[(e + 2) * 256 + ks * 64 + lane];
      }
#pragma unroll
      for (int ks = 0; ks < 4; ++ks) {
        short8v a = *(const short8v*)&ash[arow + (e + 1) * 128 + ks * 32 + q * 8];
        acc[e + 1] = __builtin_amdgcn_mfma_f32_16x16x32_bf16(a, bB[ks], acc[e + 1], 0, 0, 0);
      }
    }
    // bias + leaky_relu
    float v[16][4];
#pragma unroll
    for (int e = 0; e < 16; ++e) {
      float bv = eb[e * 256 + ut * 16 + col];
#pragma unroll
      for (int r = 0; r < 4; ++r) {
        float z = acc[e][r] + bv;
        v[e][r] = z > 0.f ? z : 0.2f * z;
      }
    }
    // eo writes via per-wave LDS transpose: write slot c*16+col (16
    // consecutive float4 -> conflict-free), read slot lane (linear).
    // Each flush = one contiguous 1KB (b,ut) region [16 u][16 e].
#pragma unroll
    for (int r = 0; r < 4; ++r) {
#pragma unroll
      for (int qq = 0; qq < 4; ++qq) {
        if (q == qq) {
#pragma unroll
          for (int c = 0; c < 4; ++c) {
            float4v o = {v[4 * c + 0][r], v[4 * c + 1][r], v[4 * c + 2][r], v[4 * c + 3][r]};
            *(float4v*)(ws + (c * 16 + col) * 4) = o;
          }
        }
        __builtin_amdgcn_wave_barrier();   // fence: write -> read (wave-synchronous LDS)
        {
          size_t b = bb + (size_t)(qq * 4 + r);
          float4v val = *(const float4v*)(ws + lane * 4);  // linear, conflict-free
          float* dst = outeo + b * 4096 + (size_t)ut * 256 + (lane & 15) * 16 + (lane >> 4) * 4;
          *(float4v*)dst = val;            // plain store: full dirty lines via L2
        }
        __builtin_amdgcn_wave_barrier();   // fence: read -> next round's write
      }
    }
  }
}

// ---------------------------------------------------------------------------
// combine kernel: out[b,g,u] = sum_e wd[b,g,e] * eo[b,u,e].  Pure streaming:
// eo rows are contiguous 64B/thread reads (4KB/wave), concat stores 256B/
// instr. 2048 blocks x 256 threads, 4 b-rows per block.
// ---------------------------------------------------------------------------
__global__ __launch_bounds__(256) void combine_kernel(
    const float* __restrict__ eo,    // [B,U,E]
    const float* __restrict__ wd,    // [B,G,E]
    float* __restrict__ outcat)      // [B, G*U]
{
  __shared__ float wl[256];
  int bt = blockIdx.x, tid = threadIdx.x;
  wl[tid] = wd[(size_t)bt * 256 + tid];   // 4 rows x 64 weights
  __syncthreads();
#pragma unroll 1
  for (int i = 0; i < 4; ++i) {
    size_t b = (size_t)bt * 4 + i;
    const float4v* ep = (const float4v*)(eo + b * 4096 + (size_t)tid * 16);
    float4v e0 = ep[0], e1 = ep[1], e2 = ep[2], e3 = ep[3];
    const float* wp = wl + i * 64;
#pragma unroll
    for (int g = 0; g < 4; ++g) {
      const float* wg = wp + g * 16;
      float s = 0.f;
      s = fmaf(wg[0],  e0[0], s); s = fmaf(wg[1],  e0[1], s);
      s = fmaf(wg[2],  e0[2], s); s = fmaf(wg[3],  e0[3], s);
      s = fmaf(wg[4],  e1[0], s); s = fmaf(wg[5],  e1[1], s);
      s = fmaf(wg[6],  e1[2], s); s = fmaf(wg[7],  e1[3], s);
      s = fmaf(wg[8],  e2[0], s); s = fmaf(wg[9],  e2[1], s);
      s = fmaf(wg[10], e2[2], s); s = fmaf(wg[11], e2[3], s);
      s = fmaf(wg[12], e3[0], s); s = fmaf(wg[13], e3[1], s);
      s = fmaf(wg[14], e3[2], s); s = fmaf(wg[15], e3[3], s);
      outcat[b * 1024 + g * 256 + tid] = s;
    }
  }
}

extern "C" void kernel_launch(void* const* d_in, const int* in_sizes, int n_in,
                              void* d_out, int out_size, void* d_ws, size_t ws_size,
                              hipStream_t stream) {
  const float* x     = (const float*)d_in[0];  // [B, E*D]
  const float* feat  = (const float*)d_in[1];  // [B, F]
  const float* ek    = (const float*)d_in[2];  // [E, D, U]
  const float* eb    = (const float*)d_in[3];  // [E, U]
  const float* gk    = (const float*)d_in[4];  // [G, F, E]
  const float* gbias = (const float*)d_in[5];  // [G, E]
  const float* gw    = (const float*)d_in[6];  // [E]
  float* out = (float*)d_out;
  float* outcat = out;
  float* outeo  = out + (size_t)NB * NG * NU;
  // workspace: [0, 2MB) dense gating weights, [2MB, 3MB) packed bf16 B frags
  float* wd  = (float*)d_ws;
  short* pbf = (short*)((char*)d_ws + (size_t)NB * NG * NE * 4);

  prep_kernel<<<512, 256, 0, stream>>>(ek, feat, gk, gbias, gw, pbf, wd);
  gemm_kernel<<<512, 512, 0, stream>>>(x, eb, pbf, outeo);
  combine_kernel<<<2048, 256, 0, stream>>>(outeo, wd, outcat);
}